// Round 9
// baseline (376.911 us; speedup 1.0000x reference)
//
#include <hip/hip_runtime.h>

typedef unsigned int uint;
typedef _Float16 half2v __attribute__((ext_vector_type(2)));
typedef _Float16 half8  __attribute__((ext_vector_type(8)));
typedef float    f32x4  __attribute__((ext_vector_type(4)));

#define BATCH   8192
#define DIM     128
#define NCLS    512
#define TMARGIN 0.3f
#define BIGF    3.402823466e+38f
#define MAXM    128
#define SEGS    8
#define TPB     8      // j-tiles per block (1024 cols per segment)

// ---------- k_prep: norms + f16 hi/lo split ----------------------------------
__global__ __launch_bounds__(256) void k_prep(
    const float* __restrict__ emb, _Float16* __restrict__ eh,
    _Float16* __restrict__ el, float* __restrict__ norms) {
  int w = threadIdx.x >> 6, lane = threadIdx.x & 63;
  int row = blockIdx.x * 4 + w;
  float2 v = reinterpret_cast<const float2*>(emb + (size_t)row * DIM)[lane];
  _Float16 h0 = (_Float16)v.x, h1 = (_Float16)v.y;
  half2v hv = {h0, h1};
  half2v lv = {(_Float16)(v.x - (float)h0), (_Float16)(v.y - (float)h1)};
  reinterpret_cast<half2v*>(eh + (size_t)row * DIM)[lane] = hv;
  reinterpret_cast<half2v*>(el + (size_t)row * DIM)[lane] = lv;
  float s = v.x * v.x + v.y * v.y;
  #pragma unroll
  for (int off = 32; off; off >>= 1) s += __shfl_xor(s, off);
  if (lane == 0) norms[row] = s;
}

// ---------- k_hp: hardest positive per row; class list gathered in LDS -------
__global__ __launch_bounds__(256) void k_hp(
    const float* __restrict__ emb, const int* __restrict__ labels,
    const float* __restrict__ norms, float* __restrict__ hp) {
  __shared__ int members[MAXM];
  __shared__ int cnt;
  int c = blockIdx.x;
  if (threadIdx.x == 0) cnt = 0;
  __syncthreads();
  for (int i = threadIdx.x; i < BATCH; i += 256)
    if (labels[i] == c) {
      int p = atomicAdd(&cnt, 1);
      if (p < MAXM) members[p] = i;
    }
  __syncthreads();
  int m = cnt < MAXM ? cnt : MAXM;
  int w = threadIdx.x >> 6, lane = threadIdx.x & 63;
  int g = lane >> 4, gl = lane & 15;
  for (int a = w; a < m; a += 4) {
    int i = members[a];
    const float4* pi = reinterpret_cast<const float4*>(emb + (size_t)i * DIM + gl * 8);
    float4 xi0 = pi[0], xi1 = pi[1];
    float ni = norms[i];
    float best = 0.f;
    for (int b = g; b < m; b += 4) {
      if (b == a) continue;
      int j = members[b];
      const float4* pj = reinterpret_cast<const float4*>(emb + (size_t)j * DIM + gl * 8);
      float4 xj0 = pj[0], xj1 = pj[1];
      float d = xi0.x*xj0.x + xi0.y*xj0.y + xi0.z*xj0.z + xi0.w*xj0.w
              + xi1.x*xj1.x + xi1.y*xj1.y + xi1.z*xj1.z + xi1.w*xj1.w;
      #pragma unroll
      for (int off = 1; off < 16; off <<= 1) d += __shfl_xor(d, off);
      float sq = fmaxf(ni + norms[j] - 2.f * d, 0.f);
      best = fmaxf(best, sq);
    }
    best = fmaxf(best, __shfl_xor(best, 16));
    best = fmaxf(best, __shfl_xor(best, 32));
    if (lane == 0) hp[i] = best > 0.f ? sqrtf(best) : 0.f;
  }
}

// ---------- k_main: full sweep, 32-phase counted-vmcnt pipeline --------------
// block = (panel 128 rows, seg 1024 cols). 8 tiles x 4 K-quarters = 32 phases.
// 3x16KB LDS bufs, stage 2 phases ahead, vmcnt(8) steady (never 0 in loop).
// LDS unit layout (16B units): hl*512 + col*4 + (kg ^ ((col>>1)&3)).
__global__ __launch_bounds__(256, 2) void k_main(
    const _Float16* __restrict__ eh, const _Float16* __restrict__ el,
    const int* __restrict__ labels, const float* __restrict__ norms,
    const float* __restrict__ hp, float* __restrict__ rowres) {
  __shared__ __align__(16) char lds[49152];
  const int t = threadIdx.x, lane = t & 63, w = t >> 6;
  const int r16 = lane & 15, kg = lane >> 4;
  const int panel = blockIdx.x >> 3, seg = blockIdx.x & 7;
  const int i0 = panel * 128, jseg = seg * 1024;

  // B-frag read byte offsets (buf/hl independent)
  int boff[8];
  #pragma unroll
  for (int n = 0; n < 8; ++n) {
    int col = 16 * n + r16;
    boff[n] = col * 64 + ((kg ^ ((col >> 1) & 3)) << 4);
  }

  // staging bases: per-thread global base (col/kgs/hl folded in) + LDS offset
  const _Float16* gbase[4];
  int lbase[4];
  #pragma unroll
  for (int it = 0; it < 4; ++it) {
    int u = (it * 4 + w) * 64 + lane;        // unit 0..1023
    int hl = u >> 9, v = u & 511;
    int col = v >> 2, s = v & 3;
    int kgs = s ^ ((col >> 1) & 3);
    gbase[it] = (hl ? el : eh) + (size_t)col * DIM + kgs * 8;
    lbase[it] = (it * 4 + w) * 1024;
  }
  auto stage = [&](int jt, int kq, int buf) {
    size_t off = (size_t)(jseg + jt * 128) * DIM + kq * 32;
    #pragma unroll
    for (int it = 0; it < 4; ++it) {
      __builtin_amdgcn_global_load_lds(
          (const __attribute__((address_space(1))) void*)(gbase[it] + off),
          (__attribute__((address_space(3))) void*)(lds + buf * 16384 + lbase[it]),
          16, 0, 0);
    }
  };

  // A fragments in registers: full K in quarters, hi+lo
  half8 ah[2][4], al[2][4];
  #pragma unroll
  for (int m = 0; m < 2; ++m) {
    size_t rbase = (size_t)(i0 + 32 * w + 16 * m + r16) * DIM + kg * 8;
    #pragma unroll
    for (int ks = 0; ks < 4; ++ks) {
      ah[m][ks] = *reinterpret_cast<const half8*>(eh + rbase + ks * 32);
      al[m][ks] = *reinterpret_cast<const half8*>(el + rbase + ks * 32);
    }
  }

  // row constants + running maxes (t-space)
  float c2[2][4], rmax[2][4], smax[2][4];
  int li[2][4];
  #pragma unroll
  for (int m = 0; m < 2; ++m)
    #pragma unroll
    for (int q = 0; q < 4; ++q) {
      int gi = i0 + 32 * w + 16 * m + 4 * kg + q;
      float nv = norms[gi], h = hp[gi];
      c2[m][q] = nv - h * h;
      li[m][q] = labels[gi];
      rmax[m][q] = -BIGF;
      smax[m][q] = -BIGF;
    }

  f32x4 acc[2][8];
  #pragma unroll
  for (int m = 0; m < 2; ++m)
    #pragma unroll
    for (int n = 0; n < 8; ++n) acc[m][n] = (f32x4){0.f, 0.f, 0.f, 0.f};

  stage(0, 0, 0);
  stage(0, 1, 1);
  int cur = 0, stg = 2, p = 0;

  for (int jt = 0; jt < TPB; ++jt) {
    float njv[8];
    int ljv[8];
    #pragma unroll
    for (int n = 0; n < 8; ++n) {
      int gj = jseg + jt * 128 + 16 * n + r16;
      njv[n] = norms[gj];
      ljv[n] = labels[gj];
    }
    #pragma unroll
    for (int kq = 0; kq < 4; ++kq) {
      int np2 = p + 2;
      if (np2 < 32) stage(np2 >> 2, np2 & 3, stg);
      if (p < 30)       asm volatile("s_waitcnt vmcnt(8)" ::: "memory");
      else if (p == 30) asm volatile("s_waitcnt vmcnt(4)" ::: "memory");
      else              asm volatile("s_waitcnt vmcnt(0)" ::: "memory");
      __builtin_amdgcn_s_barrier();
      __builtin_amdgcn_sched_barrier(0);
      const char* pb = lds + cur * 16384;
      __builtin_amdgcn_s_setprio(1);
      #pragma unroll
      for (int n = 0; n < 8; ++n) {
        half8 bh = *reinterpret_cast<const half8*>(pb + boff[n]);
        half8 bl = *reinterpret_cast<const half8*>(pb + 8192 + boff[n]);
        #pragma unroll
        for (int m = 0; m < 2; ++m) {
          acc[m][n] = __builtin_amdgcn_mfma_f32_16x16x32_f16(ah[m][kq], bh, acc[m][n], 0, 0, 0);
          acc[m][n] = __builtin_amdgcn_mfma_f32_16x16x32_f16(al[m][kq], bh, acc[m][n], 0, 0, 0);
          acc[m][n] = __builtin_amdgcn_mfma_f32_16x16x32_f16(ah[m][kq], bl, acc[m][n], 0, 0, 0);
        }
      }
      __builtin_amdgcn_s_setprio(0);
      if (kq == 3) {
        // tile epilogue (register-only, t-space): t = 2*dot - nj
        #pragma unroll
        for (int n = 0; n < 8; ++n)
          #pragma unroll
          for (int m = 0; m < 2; ++m)
            #pragma unroll
            for (int q = 0; q < 4; ++q) {
              float tv = fmaf(2.f, acc[m][n][q], -njv[n]);
              float tm = (li[m][q] != ljv[n]) ? tv : -BIGF;
              rmax[m][q] = fmaxf(rmax[m][q], tm);
              float tl = (tm < c2[m][q]) ? tm : -BIGF;
              smax[m][q] = fmaxf(smax[m][q], tl);
              acc[m][n][q] = 0.f;
            }
      }
      __builtin_amdgcn_s_barrier();
      __builtin_amdgcn_sched_barrier(0);
      cur = (cur == 2) ? 0 : cur + 1;
      stg = (stg == 2) ? 0 : stg + 1;
      ++p;
    }
  }

  // block end: reduce over the 16 col-lanes, write per-segment row results
  float2* pp = reinterpret_cast<float2*>(rowres);
  #pragma unroll
  for (int m = 0; m < 2; ++m)
    #pragma unroll
    for (int q = 0; q < 4; ++q) {
      float r = rmax[m][q], s = smax[m][q];
      #pragma unroll
      for (int off = 1; off < 16; off <<= 1) {
        r = fmaxf(r, __shfl_xor(r, off));
        s = fmaxf(s, __shfl_xor(s, off));
      }
      if (r16 == 0) {
        int gi = i0 + 32 * w + 16 * m + 4 * kg + q;
        pp[(size_t)gi * SEGS + seg] = make_float2(r, s);
      }
    }
}

// ---------- k_red: per-row combine (1 thread/row) -> per-block partial -------
__global__ __launch_bounds__(256) void k_red(
    const float* __restrict__ norms, const float* __restrict__ hp,
    const float* __restrict__ rowres, float* __restrict__ partial) {
  int row = blockIdx.x * 256 + threadIdx.x;
  const float2* pp = reinterpret_cast<const float2*>(rowres) + (size_t)row * SEGS;
  float rmax = -BIGF, smax = -BIGF;
  #pragma unroll
  for (int s = 0; s < SEGS; ++s) {
    float2 v = pp[s];
    rmax = fmaxf(rmax, v.x);
    smax = fmaxf(smax, v.y);
  }
  float ni = norms[row], h = hp[row];
  float c1 = ni - (h + TMARGIN) * (h + TMARGIN);
  bool has_neg = rmax > -1e37f;
  float neg_sq  = fmaxf(ni - rmax, 0.f);
  float semi_sq = (smax > c1) ? fmaxf(ni - smax, 0.f) : neg_sq;
  float total = 0.f, count = 0.f;
  if (h > 0.f && has_neg) {
    total = fmaxf(h - sqrtf(semi_sq) + TMARGIN, 0.f);
    count = 1.f;
  }
  #pragma unroll
  for (int off = 32; off; off >>= 1) {
    total += __shfl_xor(total, off);
    count += __shfl_xor(count, off);
  }
  __shared__ float st[4], sc[4];
  int w = threadIdx.x >> 6, lane = threadIdx.x & 63;
  if (lane == 0) { st[w] = total; sc[w] = count; }
  __syncthreads();
  if (threadIdx.x == 0) {
    float2* po = reinterpret_cast<float2*>(partial);
    po[blockIdx.x] = make_float2(st[0] + st[1] + st[2] + st[3],
                                 sc[0] + sc[1] + sc[2] + sc[3]);
  }
}

// ---------- k_out: final scalar ----------------------------------------------
__global__ void k_out(const float* __restrict__ partial, float* __restrict__ out) {
  const float2* pp = reinterpret_cast<const float2*>(partial);
  int lane = threadIdx.x;
  float T = 0.f, C = 0.f;
  if (lane < 32) { float2 a = pp[lane]; T = a.x; C = a.y; }
  #pragma unroll
  for (int off = 32; off; off >>= 1) {
    T += __shfl_xor(T, off);
    C += __shfl_xor(C, off);
  }
  if (lane == 0) out[0] = C > 0.f ? T / C : 0.f;
}

extern "C" void kernel_launch(void* const* d_in, const int* in_sizes, int n_in,
                              void* d_out, int out_size, void* d_ws, size_t ws_size,
                              hipStream_t stream) {
  const float* emb  = (const float*)d_in[0];
  const int* labels = (const int*)d_in[1];
  float* out        = (float*)d_out;

  _Float16* eh  = (_Float16*)d_ws;                     // 2 MB
  _Float16* el  = eh + (size_t)BATCH * DIM;            // 2 MB
  float* norms  = (float*)(el + (size_t)BATCH * DIM);  // 32 KB
  float* hp     = norms + BATCH;                       // 32 KB
  float* rowres = hp + BATCH;                          // 512 KB
  float* partial = rowres + (size_t)BATCH * SEGS * 2;  // 256 B

  k_prep<<<BATCH / 4, 256, 0, stream>>>(emb, eh, el, norms);
  k_hp<<<NCLS, 256, 0, stream>>>(emb, labels, norms, hp);
  k_main<<<NCLS / SEGS * SEGS * (BATCH / 128 / 8), 256, 0, stream>>>(
      eh, el, labels, norms, hp, rowres);   // 512 blocks = 64 panels x 8 segs
  k_red<<<BATCH / 256, 256, 0, stream>>>(norms, hp, rowres, partial);
  k_out<<<1, 64, 0, stream>>>(partial, out);
}

// Round 10
// 142.612 us; speedup vs baseline: 2.6429x; 2.6429x over previous
//
#include <hip/hip_runtime.h>

typedef unsigned int uint;
typedef _Float16 half2v __attribute__((ext_vector_type(2)));
typedef _Float16 half8  __attribute__((ext_vector_type(8)));
typedef float    f32x4  __attribute__((ext_vector_type(4)));

#define BATCH   8192
#define DIM     128
#define NCLS    512
#define TMARGIN 0.3f
#define BIGF    3.402823466e+38f
#define MAXM    128
#define SEGS    8
#define TPB     8      // j-tiles per block (1024 cols per segment)

// ---------- k_aux: fused prep (blocks 0..2047) + hardest-positive (2048..2559)
__global__ __launch_bounds__(256) void k_aux(
    const float* __restrict__ emb, const int* __restrict__ labels,
    _Float16* __restrict__ eh, _Float16* __restrict__ el,
    float* __restrict__ norms, float* __restrict__ hp) {
  if (blockIdx.x < 2048) {
    // ---- prep: norms + f16 hi/lo split ----
    int w = threadIdx.x >> 6, lane = threadIdx.x & 63;
    int row = blockIdx.x * 4 + w;
    float2 v = reinterpret_cast<const float2*>(emb + (size_t)row * DIM)[lane];
    _Float16 h0 = (_Float16)v.x, h1 = (_Float16)v.y;
    half2v hv = {h0, h1};
    half2v lv = {(_Float16)(v.x - (float)h0), (_Float16)(v.y - (float)h1)};
    reinterpret_cast<half2v*>(eh + (size_t)row * DIM)[lane] = hv;
    reinterpret_cast<half2v*>(el + (size_t)row * DIM)[lane] = lv;
    float s = v.x * v.x + v.y * v.y;
    #pragma unroll
    for (int off = 32; off; off >>= 1) s += __shfl_xor(s, off);
    if (lane == 0) norms[row] = s;
    return;
  }
  // ---- hardest positive for class c (self-contained: own norms) ----
  __shared__ int members[MAXM];
  __shared__ float nrm[MAXM];
  __shared__ int cnt;
  int c = blockIdx.x - 2048;
  if (threadIdx.x == 0) cnt = 0;
  __syncthreads();
  for (int i = threadIdx.x; i < BATCH; i += 256)
    if (labels[i] == c) {
      int p = atomicAdd(&cnt, 1);
      if (p < MAXM) members[p] = i;
    }
  __syncthreads();
  int m = cnt < MAXM ? cnt : MAXM;
  if (threadIdx.x < m) {
    const float4* pe = reinterpret_cast<const float4*>(
        emb + (size_t)members[threadIdx.x] * DIM);
    float s = 0.f;
    #pragma unroll
    for (int k = 0; k < 32; ++k) {
      float4 x = pe[k];
      s += x.x * x.x + x.y * x.y + x.z * x.z + x.w * x.w;
    }
    nrm[threadIdx.x] = s;
  }
  __syncthreads();
  int w = threadIdx.x >> 6, lane = threadIdx.x & 63;
  int g = lane >> 4, gl = lane & 15;
  for (int a = w; a < m; a += 4) {
    int i = members[a];
    const float4* pi = reinterpret_cast<const float4*>(emb + (size_t)i * DIM + gl * 8);
    float4 xi0 = pi[0], xi1 = pi[1];
    float ni = nrm[a];
    float best = 0.f;
    for (int b = g; b < m; b += 4) {
      if (b == a) continue;
      int j = members[b];
      const float4* pj = reinterpret_cast<const float4*>(emb + (size_t)j * DIM + gl * 8);
      float4 xj0 = pj[0], xj1 = pj[1];
      float d = xi0.x*xj0.x + xi0.y*xj0.y + xi0.z*xj0.z + xi0.w*xj0.w
              + xi1.x*xj1.x + xi1.y*xj1.y + xi1.z*xj1.z + xi1.w*xj1.w;
      #pragma unroll
      for (int off = 1; off < 16; off <<= 1) d += __shfl_xor(d, off);
      float sq = fmaxf(ni + nrm[b] - 2.f * d, 0.f);
      best = fmaxf(best, sq);
    }
    best = fmaxf(best, __shfl_xor(best, 16));
    best = fmaxf(best, __shfl_xor(best, 32));
    if (lane == 0) hp[i] = best > 0.f ? sqrtf(best) : 0.f;
  }
}

// ---------- k_main: full sweep, 32-phase counted-vmcnt, 4-buf mod-4 ----------
// block = (panel 128 rows, seg 1024 cols). 8 tiles x 4 K-quarters = 32 phases.
// 4x16KB bufs, stage 2 ahead into (p+2)&3, read p&3, ONE barrier per phase.
// vmcnt(8) steady; 4/0 drain at p=30/31. Segment norms/labels in LDS.
__global__ __launch_bounds__(256, 2) void k_main(
    const _Float16* __restrict__ eh, const _Float16* __restrict__ el,
    const int* __restrict__ labels, const float* __restrict__ norms,
    const float* __restrict__ hp, float* __restrict__ rowres) {
  __shared__ __align__(16) char lds[73728];   // 64K bufs + 4K norms + 4K labels
  const int t = threadIdx.x, lane = t & 63, w = t >> 6;
  const int r16 = lane & 15, kg = lane >> 4;
  const int panel = blockIdx.x >> 3, seg = blockIdx.x & 7;
  const int i0 = panel * 128, jseg = seg * 1024;
  float* snorm = reinterpret_cast<float*>(lds + 65536);
  int*   slab  = reinterpret_cast<int*>(lds + 69632);

  // B-frag read byte offsets (buf/hl independent)
  int boff[8];
  #pragma unroll
  for (int n = 0; n < 8; ++n) {
    int col = 16 * n + r16;
    boff[n] = col * 64 + ((kg ^ ((col >> 1) & 3)) << 4);
  }

  // staging bases
  const _Float16* gbase[4];
  int lbase[4];
  #pragma unroll
  for (int it = 0; it < 4; ++it) {
    int u = (it * 4 + w) * 64 + lane;        // unit 0..1023
    int hl = u >> 9, v = u & 511;
    int col = v >> 2, s = v & 3;
    int kgs = s ^ ((col >> 1) & 3);
    gbase[it] = (hl ? el : eh) + (size_t)col * DIM + kgs * 8;
    lbase[it] = (it * 4 + w) * 1024;
  }
  auto stage = [&](int jt, int kq, int buf) {
    size_t off = (size_t)(jseg + jt * 128) * DIM + kq * 32;
    #pragma unroll
    for (int it = 0; it < 4; ++it) {
      __builtin_amdgcn_global_load_lds(
          (const __attribute__((address_space(1))) void*)(gbase[it] + off),
          (__attribute__((address_space(3))) void*)(lds + buf * 16384 + lbase[it]),
          16, 0, 0);
    }
  };

  // segment norms/labels -> LDS (part of the vmcnt stream, before stage 0/1)
  __builtin_amdgcn_global_load_lds(
      (const __attribute__((address_space(1))) void*)(norms + jseg + t * 4),
      (__attribute__((address_space(3))) void*)(lds + 65536 + w * 1024), 16, 0, 0);
  __builtin_amdgcn_global_load_lds(
      (const __attribute__((address_space(1))) void*)(labels + jseg + t * 4),
      (__attribute__((address_space(3))) void*)(lds + 69632 + w * 1024), 16, 0, 0);

  // A fragments in registers: full K in quarters, hi+lo
  half8 ah[2][4], al[2][4];
  #pragma unroll
  for (int m = 0; m < 2; ++m) {
    size_t rbase = (size_t)(i0 + 32 * w + 16 * m + r16) * DIM + kg * 8;
    #pragma unroll
    for (int ks = 0; ks < 4; ++ks) {
      ah[m][ks] = *reinterpret_cast<const half8*>(eh + rbase + ks * 32);
      al[m][ks] = *reinterpret_cast<const half8*>(el + rbase + ks * 32);
    }
  }

  // row constants + running maxes (t-space)
  float c2[2][4], rmax[2][4], smax[2][4];
  int li[2][4];
  #pragma unroll
  for (int m = 0; m < 2; ++m)
    #pragma unroll
    for (int q = 0; q < 4; ++q) {
      int gi = i0 + 32 * w + 16 * m + 4 * kg + q;
      float nv = norms[gi], h = hp[gi];
      c2[m][q] = nv - h * h;
      li[m][q] = labels[gi];
      rmax[m][q] = -BIGF;
      smax[m][q] = -BIGF;
    }

  f32x4 acc[2][8];
  #pragma unroll
  for (int m = 0; m < 2; ++m)
    #pragma unroll
    for (int n = 0; n < 8; ++n) acc[m][n] = (f32x4){0.f, 0.f, 0.f, 0.f};

  stage(0, 0, 0);
  stage(0, 1, 1);

  int p = 0;
  for (int jt = 0; jt < TPB; ++jt) {
    // per-tile col constants from LDS (lgkm stream, not vmcnt)
    float njv[8];
    int ljv[8];
    #pragma unroll
    for (int n = 0; n < 8; ++n) {
      njv[n] = snorm[jt * 128 + 16 * n + r16];
      ljv[n] = slab[jt * 128 + 16 * n + r16];
    }
    #pragma unroll
    for (int kq = 0; kq < 4; ++kq) {
      int np2 = p + 2;
      if (np2 < 32) stage(np2 >> 2, np2 & 3, np2 & 3);
      if (p < 30)       asm volatile("s_waitcnt vmcnt(8)" ::: "memory");
      else if (p == 30) asm volatile("s_waitcnt vmcnt(4)" ::: "memory");
      else              asm volatile("s_waitcnt vmcnt(0)" ::: "memory");
      __builtin_amdgcn_s_barrier();
      __builtin_amdgcn_sched_barrier(0);
      const char* pb = lds + (p & 3) * 16384;
      __builtin_amdgcn_s_setprio(1);
      #pragma unroll
      for (int n = 0; n < 8; ++n) {
        half8 bh = *reinterpret_cast<const half8*>(pb + boff[n]);
        half8 bl = *reinterpret_cast<const half8*>(pb + 8192 + boff[n]);
        #pragma unroll
        for (int m = 0; m < 2; ++m) {
          acc[m][n] = __builtin_amdgcn_mfma_f32_16x16x32_f16(ah[m][kq], bh, acc[m][n], 0, 0, 0);
          acc[m][n] = __builtin_amdgcn_mfma_f32_16x16x32_f16(al[m][kq], bh, acc[m][n], 0, 0, 0);
          acc[m][n] = __builtin_amdgcn_mfma_f32_16x16x32_f16(ah[m][kq], bl, acc[m][n], 0, 0, 0);
        }
      }
      __builtin_amdgcn_s_setprio(0);
      if (kq == 3) {
        // tile epilogue (register-only, t-space): t = 2*dot - nj
        #pragma unroll
        for (int n = 0; n < 8; ++n)
          #pragma unroll
          for (int m = 0; m < 2; ++m)
            #pragma unroll
            for (int q = 0; q < 4; ++q) {
              float tv = fmaf(2.f, acc[m][n][q], -njv[n]);
              float tm = (li[m][q] != ljv[n]) ? tv : -BIGF;
              rmax[m][q] = fmaxf(rmax[m][q], tm);
              float tl = (tm < c2[m][q]) ? tm : -BIGF;
              smax[m][q] = fmaxf(smax[m][q], tl);
              acc[m][n][q] = 0.f;
            }
      }
      ++p;
    }
  }

  // block end: reduce over the 16 col-lanes, write per-segment row results
  float2* pp = reinterpret_cast<float2*>(rowres);
  #pragma unroll
  for (int m = 0; m < 2; ++m)
    #pragma unroll
    for (int q = 0; q < 4; ++q) {
      float r = rmax[m][q], s = smax[m][q];
      #pragma unroll
      for (int off = 1; off < 16; off <<= 1) {
        r = fmaxf(r, __shfl_xor(r, off));
        s = fmaxf(s, __shfl_xor(s, off));
      }
      if (r16 == 0) {
        int gi = i0 + 32 * w + 16 * m + 4 * kg + q;
        pp[(size_t)gi * SEGS + seg] = make_float2(r, s);
      }
    }
}

// ---------- k_fin: single block, combine segments + final scalar -------------
__global__ __launch_bounds__(1024) void k_fin(
    const float* __restrict__ norms, const float* __restrict__ hp,
    const float* __restrict__ rowres, float* __restrict__ out) {
  const float2* pp = reinterpret_cast<const float2*>(rowres);
  int t = threadIdx.x;
  float total = 0.f, count = 0.f;
  #pragma unroll
  for (int r = 0; r < 8; ++r) {
    int row = r * 1024 + t;
    float rmax = -BIGF, smax = -BIGF;
    #pragma unroll
    for (int s = 0; s < SEGS; ++s) {
      float2 v = pp[(size_t)row * SEGS + s];
      rmax = fmaxf(rmax, v.x);
      smax = fmaxf(smax, v.y);
    }
    float ni = norms[row], h = hp[row];
    float c1 = ni - (h + TMARGIN) * (h + TMARGIN);
    bool has_neg = rmax > -1e37f;
    float neg_sq  = fmaxf(ni - rmax, 0.f);
    float semi_sq = (smax > c1) ? fmaxf(ni - smax, 0.f) : neg_sq;
    if (h > 0.f && has_neg) {
      total += fmaxf(h - sqrtf(semi_sq) + TMARGIN, 0.f);
      count += 1.f;
    }
  }
  #pragma unroll
  for (int off = 32; off; off >>= 1) {
    total += __shfl_xor(total, off);
    count += __shfl_xor(count, off);
  }
  __shared__ float st[16], sc[16];
  int w = t >> 6, lane = t & 63;
  if (lane == 0) { st[w] = total; sc[w] = count; }
  __syncthreads();
  if (t < 64) {
    float T = (lane < 16) ? st[lane] : 0.f;
    float C = (lane < 16) ? sc[lane] : 0.f;
    #pragma unroll
    for (int off = 8; off; off >>= 1) {
      T += __shfl_xor(T, off);
      C += __shfl_xor(C, off);
    }
    if (lane == 0) out[0] = C > 0.f ? T / C : 0.f;
  }
}

extern "C" void kernel_launch(void* const* d_in, const int* in_sizes, int n_in,
                              void* d_out, int out_size, void* d_ws, size_t ws_size,
                              hipStream_t stream) {
  const float* emb  = (const float*)d_in[0];
  const int* labels = (const int*)d_in[1];
  float* out        = (float*)d_out;

  _Float16* eh  = (_Float16*)d_ws;                     // 2 MB
  _Float16* el  = eh + (size_t)BATCH * DIM;            // 2 MB
  float* norms  = (float*)(el + (size_t)BATCH * DIM);  // 32 KB
  float* hp     = norms + BATCH;                       // 32 KB
  float* rowres = hp + BATCH;                          // 512 KB

  k_aux<<<2048 + NCLS, 256, 0, stream>>>(emb, labels, eh, el, norms, hp);
  k_main<<<(BATCH / 128) * SEGS, 256, 0, stream>>>(eh, el, labels, norms, hp, rowres);
  k_fin<<<1, 1024, 0, stream>>>(norms, hp, rowres, out);
}

// Round 11
// 123.367 us; speedup vs baseline: 3.0552x; 1.1560x over previous
//
#include <hip/hip_runtime.h>

typedef unsigned int uint;
typedef _Float16 half2v __attribute__((ext_vector_type(2)));
typedef _Float16 half8  __attribute__((ext_vector_type(8)));
typedef float    f32x4  __attribute__((ext_vector_type(4)));

#define BATCH   8192
#define DIM     128
#define NCLS    512
#define TMARGIN 0.3f
#define BIGF    3.402823466e+38f
#define MAXM    128
#define SEGS    8
#define TPB     8      // j-tiles per block (1024 cols per segment)

// ---------- k_prep: norms + f16 (hi-only) cast + class scatter ---------------
__global__ __launch_bounds__(256) void k_prep(
    const float* __restrict__ emb, const int* __restrict__ labels,
    _Float16* __restrict__ eh, float* __restrict__ norms,
    int* __restrict__ counts, int* __restrict__ members) {
  int w = threadIdx.x >> 6, lane = threadIdx.x & 63;
  int row = blockIdx.x * 4 + w;
  float2 v = reinterpret_cast<const float2*>(emb + (size_t)row * DIM)[lane];
  half2v hv = {(_Float16)v.x, (_Float16)v.y};
  reinterpret_cast<half2v*>(eh + (size_t)row * DIM)[lane] = hv;
  float s = v.x * v.x + v.y * v.y;
  #pragma unroll
  for (int off = 32; off; off >>= 1) s += __shfl_xor(s, off);
  if (lane == 0) {
    norms[row] = s;
    int c = labels[row];
    int p = atomicAdd(&counts[c], 1);
    if (p < MAXM) members[c * MAXM + p] = row;
  }
}

// ---------- k_hp: hardest positive per row, from member lists (fp32 exact) ---
__global__ __launch_bounds__(256) void k_hp(
    const float* __restrict__ emb, const float* __restrict__ norms,
    const int* __restrict__ counts, const int* __restrict__ members,
    float* __restrict__ hp) {
  __shared__ int mem[MAXM];
  __shared__ float nrm[MAXM];
  int c = blockIdx.x;
  int m = counts[c]; if (m > MAXM) m = MAXM;
  for (int i = threadIdx.x; i < m; i += 256) {
    int j = members[c * MAXM + i];
    mem[i] = j;
    nrm[i] = norms[j];
  }
  __syncthreads();
  int w = threadIdx.x >> 6, lane = threadIdx.x & 63;
  int g = lane >> 4, gl = lane & 15;
  for (int a = w; a < m; a += 4) {
    int i = mem[a];
    const float4* pi = reinterpret_cast<const float4*>(emb + (size_t)i * DIM + gl * 8);
    float4 xi0 = pi[0], xi1 = pi[1];
    float ni = nrm[a];
    float best = 0.f;
    for (int b = g; b < m; b += 4) {
      if (b == a) continue;
      int j = mem[b];
      const float4* pj = reinterpret_cast<const float4*>(emb + (size_t)j * DIM + gl * 8);
      float4 xj0 = pj[0], xj1 = pj[1];
      float d = xi0.x*xj0.x + xi0.y*xj0.y + xi0.z*xj0.z + xi0.w*xj0.w
              + xi1.x*xj1.x + xi1.y*xj1.y + xi1.z*xj1.z + xi1.w*xj1.w;
      #pragma unroll
      for (int off = 1; off < 16; off <<= 1) d += __shfl_xor(d, off);
      float sq = fmaxf(ni + nrm[b] - 2.f * d, 0.f);
      best = fmaxf(best, sq);
    }
    best = fmaxf(best, __shfl_xor(best, 16));
    best = fmaxf(best, __shfl_xor(best, 32));
    if (lane == 0) hp[i] = best > 0.f ? sqrtf(best) : 0.f;
  }
}

// ---------- k_main: hh-only full sweep, 32-phase counted-vmcnt, 4x8KB bufs ---
// block = (panel 128 rows, seg 1024 cols). 8 tiles x 4 K-quarters = 32 phases.
// Stage 2 ahead into buf (p+2)&3, read buf p&3, ONE barrier per phase.
// vmcnt(4) steady (2 staging ops/phase); drain 2/0 at p=30/31.
__global__ __launch_bounds__(256, 2) void k_main(
    const _Float16* __restrict__ eh, const int* __restrict__ labels,
    const float* __restrict__ norms, const float* __restrict__ hp,
    float* __restrict__ rowres) {
  __shared__ __align__(16) char lds[40960];   // 4x8KB bufs + 4KB norms + 4KB labels
  const int t = threadIdx.x, lane = t & 63, w = t >> 6;
  const int r16 = lane & 15, kg = lane >> 4;
  const int panel = blockIdx.x >> 3, seg = blockIdx.x & 7;
  const int i0 = panel * 128, jseg = seg * 1024;
  float* snorm = reinterpret_cast<float*>(lds + 32768);
  int*   slab  = reinterpret_cast<int*>(lds + 36864);

  // B-frag read byte offsets within a buffer (64B row stride, k-slot XOR swz)
  int boff[8];
  #pragma unroll
  for (int n = 0; n < 8; ++n) {
    int col = 16 * n + r16;
    boff[n] = col * 64 + ((kg ^ ((col >> 1) & 3)) << 4);
  }

  // staging bases: 2 x 16B units per thread per phase (8KB buffer)
  const _Float16* gbase[2];
  int lbase[2];
  #pragma unroll
  for (int it = 0; it < 2; ++it) {
    int u = it * 256 + t;                 // unit 0..511
    int col = u >> 2, s = u & 3;
    int kgs = s ^ ((col >> 1) & 3);       // pre-swizzled global k-slot
    gbase[it] = eh + (size_t)col * DIM + kgs * 8;
    lbase[it] = it * 4096 + w * 1024;     // linear LDS dest (lane*16 added by HW)
  }
  auto stage = [&](int jt, int kq, int buf) {
    size_t off = (size_t)(jseg + jt * 128) * DIM + kq * 32;
    #pragma unroll
    for (int it = 0; it < 2; ++it) {
      __builtin_amdgcn_global_load_lds(
          (const __attribute__((address_space(1))) void*)(gbase[it] + off),
          (__attribute__((address_space(3))) void*)(lds + buf * 8192 + lbase[it]),
          16, 0, 0);
    }
  };

  // segment norms/labels -> LDS, then first two staging phases
  __builtin_amdgcn_global_load_lds(
      (const __attribute__((address_space(1))) void*)(norms + jseg + t * 4),
      (__attribute__((address_space(3))) void*)(lds + 32768 + w * 1024), 16, 0, 0);
  __builtin_amdgcn_global_load_lds(
      (const __attribute__((address_space(1))) void*)(labels + jseg + t * 4),
      (__attribute__((address_space(3))) void*)(lds + 36864 + w * 1024), 16, 0, 0);
  stage(0, 0, 0);
  stage(0, 1, 1);

  // A fragments (hi only): rows i0 + 32w + 16m + r16, full K in quarters
  half8 ah[2][4];
  #pragma unroll
  for (int m = 0; m < 2; ++m) {
    size_t rbase = (size_t)(i0 + 32 * w + 16 * m + r16) * DIM + kg * 8;
    #pragma unroll
    for (int ks = 0; ks < 4; ++ks)
      ah[m][ks] = *reinterpret_cast<const half8*>(eh + rbase + ks * 32);
  }

  // row constants + running maxes (t-space: t = 2*dot - nj, dist^2 = ni - t)
  float c2[2][4], rmax[2][4], smax[2][4];
  int li[2][4];
  #pragma unroll
  for (int m = 0; m < 2; ++m)
    #pragma unroll
    for (int q = 0; q < 4; ++q) {
      int gi = i0 + 32 * w + 16 * m + 4 * kg + q;
      float nv = norms[gi], h = hp[gi];
      c2[m][q] = nv - h * h;
      li[m][q] = labels[gi];
      rmax[m][q] = -BIGF;
      smax[m][q] = -BIGF;
    }

  f32x4 acc[2][8];
  #pragma unroll
  for (int m = 0; m < 2; ++m)
    #pragma unroll
    for (int n = 0; n < 8; ++n) acc[m][n] = (f32x4){0.f, 0.f, 0.f, 0.f};

  // sound prologue: aux + buf0/buf1 loads complete & visible before the loop
  asm volatile("s_waitcnt vmcnt(0)" ::: "memory");
  __syncthreads();

  int p = 0;
  for (int jt = 0; jt < TPB; ++jt) {
    float njv[8];
    int ljv[8];
    #pragma unroll
    for (int n = 0; n < 8; ++n) {
      njv[n] = snorm[jt * 128 + 16 * n + r16];
      ljv[n] = slab[jt * 128 + 16 * n + r16];
    }
    #pragma unroll
    for (int kq = 0; kq < 4; ++kq) {
      int np2 = p + 2;
      if (np2 < 32) stage(np2 >> 2, np2 & 3, np2 & 3);
      if (p < 30)       asm volatile("s_waitcnt vmcnt(4)" ::: "memory");
      else if (p == 30) asm volatile("s_waitcnt vmcnt(2)" ::: "memory");
      else              asm volatile("s_waitcnt vmcnt(0)" ::: "memory");
      __builtin_amdgcn_s_barrier();
      __builtin_amdgcn_sched_barrier(0);
      const char* pb = lds + (p & 3) * 8192;
      __builtin_amdgcn_s_setprio(1);
      #pragma unroll
      for (int n = 0; n < 8; ++n) {
        half8 bh = *reinterpret_cast<const half8*>(pb + boff[n]);
        #pragma unroll
        for (int m = 0; m < 2; ++m)
          acc[m][n] = __builtin_amdgcn_mfma_f32_16x16x32_f16(ah[m][kq], bh, acc[m][n], 0, 0, 0);
      }
      __builtin_amdgcn_s_setprio(0);
      if (kq == 3) {
        // tile epilogue (register-only, t-space)
        #pragma unroll
        for (int n = 0; n < 8; ++n)
          #pragma unroll
          for (int m = 0; m < 2; ++m)
            #pragma unroll
            for (int q = 0; q < 4; ++q) {
              float tv = fmaf(2.f, acc[m][n][q], -njv[n]);
              float tm = (li[m][q] != ljv[n]) ? tv : -BIGF;
              rmax[m][q] = fmaxf(rmax[m][q], tm);
              float tl = (tm < c2[m][q]) ? tm : -BIGF;
              smax[m][q] = fmaxf(smax[m][q], tl);
              acc[m][n][q] = 0.f;
            }
      }
      ++p;
    }
  }

  // block end: reduce over the 16 col-lanes, write per-segment row results
  float2* pp = reinterpret_cast<float2*>(rowres);
  #pragma unroll
  for (int m = 0; m < 2; ++m)
    #pragma unroll
    for (int q = 0; q < 4; ++q) {
      float r = rmax[m][q], s = smax[m][q];
      #pragma unroll
      for (int off = 1; off < 16; off <<= 1) {
        r = fmaxf(r, __shfl_xor(r, off));
        s = fmaxf(s, __shfl_xor(s, off));
      }
      if (r16 == 0) {
        int gi = i0 + 32 * w + 16 * m + 4 * kg + q;
        pp[(size_t)gi * SEGS + seg] = make_float2(r, s);
      }
    }
}

// ---------- k_fin: single block, combine segments + final scalar -------------
__global__ __launch_bounds__(1024) void k_fin(
    const float* __restrict__ norms, const float* __restrict__ hp,
    const float* __restrict__ rowres, float* __restrict__ out) {
  const float2* pp = reinterpret_cast<const float2*>(rowres);
  int t = threadIdx.x;
  float total = 0.f, count = 0.f;
  #pragma unroll
  for (int r = 0; r < 8; ++r) {
    int row = r * 1024 + t;
    float rmax = -BIGF, smax = -BIGF;
    #pragma unroll
    for (int s = 0; s < SEGS; ++s) {
      float2 v = pp[(size_t)row * SEGS + s];
      rmax = fmaxf(rmax, v.x);
      smax = fmaxf(smax, v.y);
    }
    float ni = norms[row], h = hp[row];
    float c1 = ni - (h + TMARGIN) * (h + TMARGIN);
    bool has_neg = rmax > -1e37f;
    float neg_sq  = fmaxf(ni - rmax, 0.f);
    float semi_sq = (smax > c1) ? fmaxf(ni - smax, 0.f) : neg_sq;
    if (h > 0.f && has_neg) {
      total += fmaxf(h - sqrtf(semi_sq) + TMARGIN, 0.f);
      count += 1.f;
    }
  }
  #pragma unroll
  for (int off = 32; off; off >>= 1) {
    total += __shfl_xor(total, off);
    count += __shfl_xor(count, off);
  }
  __shared__ float st[16], sc[16];
  int w = t >> 6, lane = t & 63;
  if (lane == 0) { st[w] = total; sc[w] = count; }
  __syncthreads();
  if (t < 64) {
    float T = (lane < 16) ? st[lane] : 0.f;
    float C = (lane < 16) ? sc[lane] : 0.f;
    #pragma unroll
    for (int off = 8; off; off >>= 1) {
      T += __shfl_xor(T, off);
      C += __shfl_xor(C, off);
    }
    if (lane == 0) out[0] = C > 0.f ? T / C : 0.f;
  }
}

extern "C" void kernel_launch(void* const* d_in, const int* in_sizes, int n_in,
                              void* d_out, int out_size, void* d_ws, size_t ws_size,
                              hipStream_t stream) {
  const float* emb  = (const float*)d_in[0];
  const int* labels = (const int*)d_in[1];
  float* out        = (float*)d_out;

  _Float16* eh  = (_Float16*)d_ws;                     // 2 MB
  float* norms  = (float*)(eh + (size_t)BATCH * DIM);  // 32 KB
  float* hp     = norms + BATCH;                       // 32 KB
  int* counts   = (int*)(hp + BATCH);                  // 2 KB
  int* members  = counts + NCLS;                       // 256 KB
  float* rowres = (float*)(members + NCLS * MAXM);     // 512 KB

  hipMemsetAsync(counts, 0, NCLS * sizeof(int), stream);
  k_prep<<<BATCH / 4, 256, 0, stream>>>(emb, labels, eh, norms, counts, members);
  k_hp<<<NCLS, 256, 0, stream>>>(emb, norms, counts, members, hp);
  k_main<<<(BATCH / 128) * SEGS, 256, 0, stream>>>(eh, labels, norms, hp, rowres);
  k_fin<<<1, 1024, 0, stream>>>(norms, hp, rowres, out);
}

// Round 12
// 70.412 us; speedup vs baseline: 5.3529x; 1.7521x over previous
//
#include <hip/hip_runtime.h>

typedef unsigned int uint;
typedef _Float16 half2v __attribute__((ext_vector_type(2)));
typedef _Float16 half8  __attribute__((ext_vector_type(8)));
typedef float    f32x4  __attribute__((ext_vector_type(4)));

#define BATCH   8192
#define DIM     128
#define NCLS    512
#define TMARGIN 0.3f
#define BIGF    3.402823466e+38f
#define MAXM    128
#define SEGS    8
#define TPB     8      // j-tiles per block (1024 cols per segment)

// ---------- k_prep: norms + f16 (hi-only) cast + class scatter ---------------
__global__ __launch_bounds__(256) void k_prep(
    const float* __restrict__ emb, const int* __restrict__ labels,
    _Float16* __restrict__ eh, float* __restrict__ norms,
    int* __restrict__ counts, int* __restrict__ members) {
  int w = threadIdx.x >> 6, lane = threadIdx.x & 63;
  int row = blockIdx.x * 4 + w;
  float2 v = reinterpret_cast<const float2*>(emb + (size_t)row * DIM)[lane];
  half2v hv = {(_Float16)v.x, (_Float16)v.y};
  reinterpret_cast<half2v*>(eh + (size_t)row * DIM)[lane] = hv;
  float s = v.x * v.x + v.y * v.y;
  #pragma unroll
  for (int off = 32; off; off >>= 1) s += __shfl_xor(s, off);
  if (lane == 0) {
    norms[row] = s;
    int c = labels[row];
    int p = atomicAdd(&counts[c], 1);
    if (p < MAXM) members[c * MAXM + p] = row;
  }
}

// ---------- k_hp: hardest positive per row, from member lists (fp32 exact) ---
__global__ __launch_bounds__(256) void k_hp(
    const float* __restrict__ emb, const float* __restrict__ norms,
    const int* __restrict__ counts, const int* __restrict__ members,
    float* __restrict__ hp) {
  __shared__ int mem[MAXM];
  __shared__ float nrm[MAXM];
  int c = blockIdx.x;
  int m = counts[c]; if (m > MAXM) m = MAXM;
  for (int i = threadIdx.x; i < m; i += 256) {
    int j = members[c * MAXM + i];
    mem[i] = j;
    nrm[i] = norms[j];
  }
  __syncthreads();
  int w = threadIdx.x >> 6, lane = threadIdx.x & 63;
  int g = lane >> 4, gl = lane & 15;
  for (int a = w; a < m; a += 4) {
    int i = mem[a];
    const float4* pi = reinterpret_cast<const float4*>(emb + (size_t)i * DIM + gl * 8);
    float4 xi0 = pi[0], xi1 = pi[1];
    float ni = nrm[a];
    float best = 0.f;
    for (int b = g; b < m; b += 4) {
      if (b == a) continue;
      int j = mem[b];
      const float4* pj = reinterpret_cast<const float4*>(emb + (size_t)j * DIM + gl * 8);
      float4 xj0 = pj[0], xj1 = pj[1];
      float d = xi0.x*xj0.x + xi0.y*xj0.y + xi0.z*xj0.z + xi0.w*xj0.w
              + xi1.x*xj1.x + xi1.y*xj1.y + xi1.z*xj1.z + xi1.w*xj1.w;
      #pragma unroll
      for (int off = 1; off < 16; off <<= 1) d += __shfl_xor(d, off);
      float sq = fmaxf(ni + nrm[b] - 2.f * d, 0.f);
      best = fmaxf(best, sq);
    }
    best = fmaxf(best, __shfl_xor(best, 16));
    best = fmaxf(best, __shfl_xor(best, 32));
    if (lane == 0) hp[i] = best > 0.f ? sqrtf(best) : 0.f;
  }
}

// ---------- k_main: hh-only full sweep, 32-phase counted-vmcnt, 4x8KB bufs ---
// block = (panel 128 rows, seg 1024 cols). 8 tiles x 4 K-quarters = 32 phases.
// Stage 2 ahead into buf (p+2)&3, read buf p&3, ONE barrier per phase.
// vmcnt(4) steady (2 staging ops/phase); drain 2/0 at p=30/31.
__global__ __launch_bounds__(256, 2) void k_main(
    const _Float16* __restrict__ eh, const int* __restrict__ labels,
    const float* __restrict__ norms, const float* __restrict__ hp,
    float* __restrict__ rowres) {
  __shared__ __align__(16) char lds[40960];   // 4x8KB bufs + 4KB norms + 4KB labels
  const int t = threadIdx.x, lane = t & 63, w = t >> 6;
  const int r16 = lane & 15, kg = lane >> 4;
  const int panel = blockIdx.x >> 3, seg = blockIdx.x & 7;
  const int i0 = panel * 128, jseg = seg * 1024;
  float* snorm = reinterpret_cast<float*>(lds + 32768);
  int*   slab  = reinterpret_cast<int*>(lds + 36864);

  // B-frag read byte offsets within a buffer (64B row stride, k-slot XOR swz)
  int boff[8];
  #pragma unroll
  for (int n = 0; n < 8; ++n) {
    int col = 16 * n + r16;
    boff[n] = col * 64 + ((kg ^ ((col >> 1) & 3)) << 4);
  }

  // staging bases: 2 x 16B units per thread per phase (8KB buffer)
  const _Float16* gbase[2];
  int lbase[2];
  #pragma unroll
  for (int it = 0; it < 2; ++it) {
    int u = it * 256 + t;                 // unit 0..511
    int col = u >> 2, s = u & 3;
    int kgs = s ^ ((col >> 1) & 3);       // pre-swizzled global k-slot
    gbase[it] = eh + (size_t)col * DIM + kgs * 8;
    lbase[it] = it * 4096 + w * 1024;     // linear LDS dest (lane*16 added by HW)
  }
  auto stage = [&](int jt, int kq, int buf) {
    size_t off = (size_t)(jseg + jt * 128) * DIM + kq * 32;
    #pragma unroll
    for (int it = 0; it < 2; ++it) {
      __builtin_amdgcn_global_load_lds(
          (const __attribute__((address_space(1))) void*)(gbase[it] + off),
          (__attribute__((address_space(3))) void*)(lds + buf * 8192 + lbase[it]),
          16, 0, 0);
    }
  };

  // segment norms/labels -> LDS, then first two staging phases
  __builtin_amdgcn_global_load_lds(
      (const __attribute__((address_space(1))) void*)(norms + jseg + t * 4),
      (__attribute__((address_space(3))) void*)(lds + 32768 + w * 1024), 16, 0, 0);
  __builtin_amdgcn_global_load_lds(
      (const __attribute__((address_space(1))) void*)(labels + jseg + t * 4),
      (__attribute__((address_space(3))) void*)(lds + 36864 + w * 1024), 16, 0, 0);
  stage(0, 0, 0);
  stage(0, 1, 1);

  // A fragments (hi only): rows i0 + 32w + 16m + r16, full K in quarters
  half8 ah[2][4];
  #pragma unroll
  for (int m = 0; m < 2; ++m) {
    size_t rbase = (size_t)(i0 + 32 * w + 16 * m + r16) * DIM + kg * 8;
    #pragma unroll
    for (int ks = 0; ks < 4; ++ks)
      ah[m][ks] = *reinterpret_cast<const half8*>(eh + rbase + ks * 32);
  }

  // row constants + running maxes (t-space: t = 2*dot - nj, dist^2 = ni - t)
  float c2[2][4], rmax[2][4], smax[2][4];
  int li[2][4];
  #pragma unroll
  for (int m = 0; m < 2; ++m)
    #pragma unroll
    for (int q = 0; q < 4; ++q) {
      int gi = i0 + 32 * w + 16 * m + 4 * kg + q;
      float nv = norms[gi], h = hp[gi];
      c2[m][q] = nv - h * h;
      li[m][q] = labels[gi];
      rmax[m][q] = -BIGF;
      smax[m][q] = -BIGF;
    }

  f32x4 acc[2][8];
  #pragma unroll
  for (int m = 0; m < 2; ++m)
    #pragma unroll
    for (int n = 0; n < 8; ++n) acc[m][n] = (f32x4){0.f, 0.f, 0.f, 0.f};

  // sound prologue: aux + buf0/buf1 loads complete & visible before the loop
  asm volatile("s_waitcnt vmcnt(0)" ::: "memory");
  __syncthreads();

  int p = 0;
  for (int jt = 0; jt < TPB; ++jt) {
    float njv[8];
    int ljv[8];
    #pragma unroll
    for (int n = 0; n < 8; ++n) {
      njv[n] = snorm[jt * 128 + 16 * n + r16];
      ljv[n] = slab[jt * 128 + 16 * n + r16];
    }
    #pragma unroll
    for (int kq = 0; kq < 4; ++kq) {
      int np2 = p + 2;
      if (np2 < 32) stage(np2 >> 2, np2 & 3, np2 & 3);
      if (p < 30)       asm volatile("s_waitcnt vmcnt(4)" ::: "memory");
      else if (p == 30) asm volatile("s_waitcnt vmcnt(2)" ::: "memory");
      else              asm volatile("s_waitcnt vmcnt(0)" ::: "memory");
      __builtin_amdgcn_s_barrier();
      __builtin_amdgcn_sched_barrier(0);
      const char* pb = lds + (p & 3) * 8192;
      __builtin_amdgcn_s_setprio(1);
      #pragma unroll
      for (int n = 0; n < 8; ++n) {
        half8 bh = *reinterpret_cast<const half8*>(pb + boff[n]);
        #pragma unroll
        for (int m = 0; m < 2; ++m)
          acc[m][n] = __builtin_amdgcn_mfma_f32_16x16x32_f16(ah[m][kq], bh, acc[m][n], 0, 0, 0);
      }
      __builtin_amdgcn_s_setprio(0);
      if (kq == 3) {
        // tile epilogue (register-only, t-space)
        #pragma unroll
        for (int n = 0; n < 8; ++n)
          #pragma unroll
          for (int m = 0; m < 2; ++m)
            #pragma unroll
            for (int q = 0; q < 4; ++q) {
              float tv = fmaf(2.f, acc[m][n][q], -njv[n]);
              float tm = (li[m][q] != ljv[n]) ? tv : -BIGF;
              rmax[m][q] = fmaxf(rmax[m][q], tm);
              float tl = (tm < c2[m][q]) ? tm : -BIGF;
              smax[m][q] = fmaxf(smax[m][q], tl);
              acc[m][n][q] = 0.f;
            }
      }
      ++p;
    }
  }

  // block end: reduce over the 16 col-lanes, write per-segment row results
  float2* pp = reinterpret_cast<float2*>(rowres);
  #pragma unroll
  for (int m = 0; m < 2; ++m)
    #pragma unroll
    for (int q = 0; q < 4; ++q) {
      float r = rmax[m][q], s = smax[m][q];
      #pragma unroll
      for (int off = 1; off < 16; off <<= 1) {
        r = fmaxf(r, __shfl_xor(r, off));
        s = fmaxf(s, __shfl_xor(s, off));
      }
      if (r16 == 0) {
        int gi = i0 + 32 * w + 16 * m + 4 * kg + q;
        pp[(size_t)gi * SEGS + seg] = make_float2(r, s);
      }
    }
}

// ---------- k_red: per-row combine (1 thread/row, 32 blocks) -----------------
__global__ __launch_bounds__(256) void k_red(
    const float* __restrict__ norms, const float* __restrict__ hp,
    const float* __restrict__ rowres, float* __restrict__ partial) {
  int row = blockIdx.x * 256 + threadIdx.x;
  const float2* pp = reinterpret_cast<const float2*>(rowres) + (size_t)row * SEGS;
  float rmax = -BIGF, smax = -BIGF;
  #pragma unroll
  for (int s = 0; s < SEGS; ++s) {
    float2 v = pp[s];
    rmax = fmaxf(rmax, v.x);
    smax = fmaxf(smax, v.y);
  }
  float ni = norms[row], h = hp[row];
  float c1 = ni - (h + TMARGIN) * (h + TMARGIN);
  bool has_neg = rmax > -1e37f;
  float neg_sq  = fmaxf(ni - rmax, 0.f);
  float semi_sq = (smax > c1) ? fmaxf(ni - smax, 0.f) : neg_sq;
  float total = 0.f, count = 0.f;
  if (h > 0.f && has_neg) {
    total = fmaxf(h - sqrtf(semi_sq) + TMARGIN, 0.f);
    count = 1.f;
  }
  #pragma unroll
  for (int off = 32; off; off >>= 1) {
    total += __shfl_xor(total, off);
    count += __shfl_xor(count, off);
  }
  __shared__ float st[4], sc[4];
  int w = threadIdx.x >> 6, lane = threadIdx.x & 63;
  if (lane == 0) { st[w] = total; sc[w] = count; }
  __syncthreads();
  if (threadIdx.x == 0) {
    float2* po = reinterpret_cast<float2*>(partial);
    po[blockIdx.x] = make_float2(st[0] + st[1] + st[2] + st[3],
                                 sc[0] + sc[1] + sc[2] + sc[3]);
  }
}

// ---------- k_out: final scalar ----------------------------------------------
__global__ void k_out(const float* __restrict__ partial, float* __restrict__ out) {
  const float2* pp = reinterpret_cast<const float2*>(partial);
  int lane = threadIdx.x;
  float T = 0.f, C = 0.f;
  if (lane < 32) { float2 a = pp[lane]; T = a.x; C = a.y; }
  #pragma unroll
  for (int off = 32; off; off >>= 1) {
    T += __shfl_xor(T, off);
    C += __shfl_xor(C, off);
  }
  if (lane == 0) out[0] = C > 0.f ? T / C : 0.f;
}

extern "C" void kernel_launch(void* const* d_in, const int* in_sizes, int n_in,
                              void* d_out, int out_size, void* d_ws, size_t ws_size,
                              hipStream_t stream) {
  const float* emb  = (const float*)d_in[0];
  const int* labels = (const int*)d_in[1];
  float* out        = (float*)d_out;

  _Float16* eh  = (_Float16*)d_ws;                     // 2 MB
  float* norms  = (float*)(eh + (size_t)BATCH * DIM);  // 32 KB
  float* hp     = norms + BATCH;                       // 32 KB
  int* counts   = (int*)(hp + BATCH);                  // 2 KB
  int* members  = counts + NCLS;                       // 256 KB
  float* rowres = (float*)(members + NCLS * MAXM);     // 512 KB
  float* partial = rowres + (size_t)BATCH * SEGS * 2;  // 256 B

  hipMemsetAsync(counts, 0, NCLS * sizeof(int), stream);
  k_prep<<<BATCH / 4, 256, 0, stream>>>(emb, labels, eh, norms, counts, members);
  k_hp<<<NCLS, 256, 0, stream>>>(emb, norms, counts, members, hp);
  k_main<<<(BATCH / 128) * SEGS, 256, 0, stream>>>(eh, labels, norms, hp, rowres);
  k_red<<<BATCH / 256, 256, 0, stream>>>(norms, hp, rowres, partial);
  k_out<<<1, 64, 0, stream>>>(partial, out);
}